// Round 2
// baseline (36210.034 us; speedup 1.0000x reference)
//
#include <hip/hip_runtime.h>
#include <math.h>

#define B_ROWS 4096
#define D_DIM  768
#define M_ROWS 100000
#define K_TOP  10

#define RB   16      // rows per block
#define GQ   64      // m-groups (threads per row)
#define MM   4       // evidence rows per thread per j-step
#define NJ   391     // GQ*MM*NJ = 100096 >= 100000
#define NT   1024    // threads per block (16 waves)
#define XPAD 772     // LDS x-row stride (floats)
#define DQ4  192     // D_DIM/4

// LDS layout (floats):
//   [0,12352)      x tile [16][772]                  (phase 1+compute)
//   [0,10240)      cs: fp32 cand scores [16][64][10] (phase 2, after sync)
//   [10240,20480)  ci: cand indices     [16][64][10]
//   [20480,20736)  cnd: merged top-16 idx [16][16]
//   [20736,21248)  rsd: fp64 rescores [16][16] (as doubles)
__global__ __launch_bounds__(NT, 4) void retr_fused(
    const float* __restrict__ x, const float* __restrict__ E,
    float* __restrict__ out)
{
  __shared__ float smem[21248];
  const int t = threadIdx.x;
  const int r = t & 15;            // row within block
  const int g = t >> 4;            // m-group 0..63
  const int rb0 = blockIdx.x * RB;

  // ---- phase 1: stage 16 x rows into LDS (coalesced float4) ----
  {
    const float4* xg = (const float4*)(x + (size_t)rb0 * D_DIM);
    for (int q = t; q < RB * DQ4; q += NT) {
      int row = q / DQ4, c4 = q % DQ4;
      float4 v = xg[q];
      *(float4*)(smem + row * XPAD + c4 * 4) = v;
    }
  }
  __syncthreads();

  // ---- per-thread running top-10 (sorted desc, static-indexed) ----
  float ts[K_TOP]; int ti[K_TOP];
#pragma unroll
  for (int q = 0; q < K_TOP; ++q) { ts[q] = -INFINITY; ti[q] = 0x7fffffff; }

  const float4* xr4 = (const float4*)(smem + r * XPAD);

  for (int j = 0; j < NJ; ++j) {
    const int m0 = (g + (j << 6)) * MM;     // this thread's 4 evidence rows
    const float4* ep[MM];
#pragma unroll
    for (int mm = 0; mm < MM; ++mm) {
      int ml = m0 + mm;
      int mc = (ml < M_ROWS) ? ml : (M_ROWS - 1);   // clamp tail loads
      ep[mm] = (const float4*)(E + (size_t)mc * D_DIM);
    }
    float4 acc[MM];
#pragma unroll
    for (int mm = 0; mm < MM; ++mm) acc[mm] = make_float4(0.f, 0.f, 0.f, 0.f);

    // 4 independent fp32 chains per m (accuracy ~1e-5 + ILP)
#pragma unroll 4
    for (int dq = 0; dq < DQ4; ++dq) {
      float4 xv = xr4[dq];
#pragma unroll
      for (int mm = 0; mm < MM; ++mm) {
        float4 e = ep[mm][dq];
        acc[mm].x += e.x * xv.x;
        acc[mm].y += e.y * xv.y;
        acc[mm].z += e.z * xv.z;
        acc[mm].w += e.w * xv.w;
      }
    }

#pragma unroll
    for (int mm = 0; mm < MM; ++mm) {
      int ml = m0 + mm;
      float s = (acc[mm].x + acc[mm].y) + (acc[mm].z + acc[mm].w);
      if (ml < M_ROWS && s > ts[K_TOP - 1]) {
        ts[K_TOP - 1] = s; ti[K_TOP - 1] = ml;
#pragma unroll
        for (int q = K_TOP - 1; q > 0; --q) {
          if (ts[q] > ts[q - 1]) {
            float tf = ts[q]; ts[q] = ts[q - 1]; ts[q - 1] = tf;
            int   tq = ti[q]; ti[q] = ti[q - 1]; ti[q - 1] = tq;
          }
        }
      }
    }
  }

  __syncthreads();                 // x tile done; reuse LDS
  float*  cs  = smem;
  int*    ci  = (int*)(smem + 10240);
  int*    cnd = (int*)(smem + 20480);
  double* rsd = (double*)(smem + 20736);

#pragma unroll
  for (int q = 0; q < K_TOP; ++q) {
    cs[(r * GQ + g) * K_TOP + q] = ts[q];
    ci[(r * GQ + g) * K_TOP + q] = ti[q];
  }
  __syncthreads();

  const int w = t >> 6;            // wave id = row within block
  const int lane = t & 63;

  // ---- phase 2: wave w merges row (rb0+w)'s 64 sorted lists -> top-16 ----
  {
    float ms[K_TOP]; int mi[K_TOP];
#pragma unroll
    for (int q = 0; q < K_TOP; ++q) {
      ms[q] = cs[(w * GQ + lane) * K_TOP + q];
      mi[q] = ci[(w * GQ + lane) * K_TOP + q];
    }
    for (int o = 0; o < 16; ++o) {
      float hs = ms[0]; int hi = mi[0];   // my head (list is sorted desc)
      float bs = hs;    int bi = hi;
#pragma unroll
      for (int mk = 1; mk <= 32; mk <<= 1) {   // 64-lane argmax, idx tiebreak
        float qs = __shfl_xor(bs, mk, 64);
        int   qi = __shfl_xor(bi, mk, 64);
        if (qs > bs || (qs == bs && qi < bi)) { bs = qs; bi = qi; }
      }
      bool win = (hs == bs) && (hi == bi);  // indices unique -> one winner
      if (win) {
#pragma unroll
        for (int q = 0; q < K_TOP - 1; ++q) { ms[q] = ms[q + 1]; mi[q] = mi[q + 1]; }
        ms[K_TOP - 1] = -INFINITY; mi[K_TOP - 1] = 0x7fffffff;
      }
      if (lane == 0) cnd[w * 16 + o] = bi;
    }
  }
  __syncthreads();

  // ---- phase 3: fp64 rescore of the 16 candidates (4 lanes per cand) ----
  {
    int cand = lane >> 2, p = lane & 3;
    int cid = cnd[w * 16 + cand];
    const float* Er = E + (size_t)cid * D_DIM + p * 192;
    const float* Xr = x + (size_t)(rb0 + w) * D_DIM + p * 192;
    double s = 0.0;
#pragma unroll 8
    for (int d = 0; d < 192; ++d) s += (double)Xr[d] * (double)Er[d];
    s += __shfl_xor(s, 1, 64);     // deterministic ((s0+s1)+(s2+s3))
    s += __shfl_xor(s, 2, 64);
    if (p == 0) rsd[w * 16 + cand] = s;
  }
  __syncthreads();

  // ---- phase 4: rank 16 by exact fp64 score, write final top-10 ----
  if (lane == 0) {
    const int row = rb0 + w;
    for (int o = 0; o < K_TOP; ++o) {
      double bsv = rsd[w * 16 + 0]; int bci = cnd[w * 16 + 0]; int b = 0;
      for (int q = 1; q < 16; ++q) {
        double v = rsd[w * 16 + q]; int c = cnd[w * 16 + q];
        if (v > bsv || (v == bsv && c < bci)) { bsv = v; bci = c; b = q; }
      }
      out[(size_t)row * K_TOP + o] = (float)bsv;
      out[(size_t)B_ROWS * K_TOP + (size_t)row * K_TOP + o] = (float)bci;
      rsd[w * 16 + b] = -1.0e300;   // consume (LDS, runtime index ok)
    }
  }
}

extern "C" void kernel_launch(void* const* d_in, const int* in_sizes, int n_in,
                              void* d_out, int out_size, void* d_ws, size_t ws_size,
                              hipStream_t stream) {
  const float* x = (const float*)d_in[0];
  const float* E = (const float*)d_in[1];
  // d_in[2] is k == 10, compile-time constant here.
  float* out = (float*)d_out;
  retr_fused<<<dim3(B_ROWS / RB), NT, 0, stream>>>(x, E, out);
}

// Round 3
// 1763.979 us; speedup vs baseline: 20.5275x; 20.5275x over previous
//
#include <hip/hip_runtime.h>
#include <math.h>
#include <stdint.h>

#define B_ROWS 4096
#define D_DIM  768
#define M_ROWS 100000
#define K_TOP  10

// ---------------- MFMA-path constants ----------------
#define KSTEPS 48          // 768 / 16
#define E32N   3125        // evidence 32-row tiles (100000/32 exact)
#define B32N   128         // batch 32-row tiles (4096/32)
#define NGRP   16          // evidence groups (grid.y)
#define NBB    16          // batch blocks (grid.x), 256 rows each
#define NITER_TOT 391      // ceil(3125/8): block-iterations of 256 evid rows
#define CAND   12          // candidates kept per (row, group)
#define KCN    12          // k-chunks of 64 (12*64 = 768)

typedef _Float16 f16;
typedef _Float16 f16x8 __attribute__((ext_vector_type(8)));
typedef float   f32x16 __attribute__((ext_vector_type(16)));

// workspace layout (bytes)
#define XF_BYTES (128ull * 48 * 1024)        //   6,291,456
#define EF_OFF   XF_BYTES
#define EF_BYTES (3125ull * 48 * 1024)       // 153,600,000
#define CS_OFF   (EF_OFF + EF_BYTES)
#define CS_BYTES (4096ull * NGRP * CAND * 4) //   3,145,728
#define CI_OFF   (CS_OFF + CS_BYTES)
#define CI_BYTES (4096ull * NGRP * CAND * 4)
#define WS_NEED  (CI_OFF + CI_BYTES)         // ~166 MB

// ---------------------------------------------------------------------------
// Convert fp32 [rows][768] -> f16 fragment-tiled [band32][ks48][lane64][j8].
// Element: dst frag value (l,j) = src[band*32 + (l&31)][ks*16 + 8*(l>>5) + j]
// (A-frag and B-frag of mfma_f32_32x32x16_f16 use the same (l,j)->k map, so
//  any consistent k-bijection yields correct dot products.)
// ---------------------------------------------------------------------------
__global__ __launch_bounds__(256) void convert_frag(
    const float* __restrict__ src, f16* __restrict__ dst, int nband)
{
  int tid  = blockIdx.x * 256 + threadIdx.x;
  int l    = tid & 63;
  int rest = tid >> 6;
  int ks   = rest % KSTEPS;
  int band = rest / KSTEPS;
  if (band >= nband) return;
  int row = band * 32 + (l & 31);
  int k0  = ks * 16 + 8 * (l >> 5);
  const float* s = src + (size_t)row * D_DIM + k0;
  float4 v0 = *(const float4*)s;
  float4 v1 = *(const float4*)(s + 4);
  f16x8 o;
  o[0] = (f16)v0.x; o[1] = (f16)v0.y; o[2] = (f16)v0.z; o[3] = (f16)v0.w;
  o[4] = (f16)v1.x; o[5] = (f16)v1.y; o[6] = (f16)v1.z; o[7] = (f16)v1.w;
  *(f16x8*)(dst + (((size_t)band * KSTEPS + ks) << 9) + l * 8) = o;
}

// ---------------------------------------------------------------------------
// sorted top-10 insert (descending), static-indexed
// ---------------------------------------------------------------------------
__device__ __forceinline__ void ins10(float (&ts)[10], int (&ti)[10],
                                      float s, int idx)
{
  ts[9] = s; ti[9] = idx;
#pragma unroll
  for (int q = 9; q > 0; --q) {
    if (ts[q] > ts[q - 1]) {
      float a = ts[q]; ts[q] = ts[q - 1]; ts[q - 1] = a;
      int   b = ti[q]; ti[q] = ti[q - 1]; ti[q - 1] = b;
    }
  }
}

// ---------------------------------------------------------------------------
// GEMM + fused per-lane top-k.
// Block: 512 thr = 8 waves = 2 evid-waves x 4 batch-waves.
// Per block-iteration: 256 evid rows x 256 batch cols, K=768.
// Per wave: 4 evid-tiles x 2 batch-tiles of mfma_f32_32x32x16_f16 (swapped:
// A=E so C rows = evid, C col = lane&31 = batch -> topk is lane-local).
// ---------------------------------------------------------------------------
__global__ __launch_bounds__(512, 2) void gemm_topk(
    const f16* __restrict__ Ef, const f16* __restrict__ Xf,
    float* __restrict__ cs, int* __restrict__ ci)
{
  __shared__ f16 lds[2][32768];   // 2 x 64KB: frags f=0..31 E, 32..63 x

  const int t    = threadIdx.x;
  const int lane = t & 63;
  const int w    = t >> 6;      // 0..7
  const int ew   = w >> 2;      // 0..1  evid-wave
  const int bw   = w & 3;       // 0..3  batch-wave
  const int bb   = blockIdx.x;  // batch block (256 rows)
  const int g    = blockIdx.y;  // evid group
  const int niter = 24 + (g < (NITER_TOT - 16 * 24) ? 1 : 0); // 391 = 16*24+7

  float ts0[10], ts1[10]; int ti0[10], ti1[10];
#pragma unroll
  for (int q = 0; q < 10; ++q) {
    ts0[q] = -INFINITY; ts1[q] = -INFINITY;
    ti0[q] = 0x7fffffff; ti1[q] = 0x7fffffff;
  }

  for (int j = 0; j < niter; ++j) {
    const int it = g + NGRP * j;       // global block-iteration
    const int e32base = it * 8;

    f32x16 acc0[4], acc1[4];
#pragma unroll
    for (int e = 0; e < 4; ++e) {
#pragma unroll
      for (int q = 0; q < 16; ++q) { acc0[e][q] = 0.f; acc1[e][q] = 0.f; }
    }

    // stage one k-chunk (64 frags, 8 per wave) into buf
    auto STAGE = [&](int kc, int bufi) {
#pragma unroll
      for (int ff = 0; ff < 8; ++ff) {
        int f = w * 8 + ff;
        const f16* src;
        if (f < 32) {                       // E frag: et = f>>2, kk = f&3
          int et = f >> 2, kk = f & 3;
          int e32 = e32base + et; if (e32 > E32N - 1) e32 = E32N - 1;
          src = Ef + (((size_t)e32 * KSTEPS + kc * 4 + kk) << 9);
        } else {                            // x frag
          int f2 = f - 32; int bt = f2 >> 2, kk = f2 & 3;
          int b32 = bb * 8 + bt;
          src = Xf + (((size_t)b32 * KSTEPS + kc * 4 + kk) << 9);
        }
        const f16* sp = src + lane * 8;
        f16* dp = &lds[bufi][f << 9] + lane * 8;
        __builtin_amdgcn_global_load_lds(
            (const __attribute__((address_space(1))) void*)(uintptr_t)sp,
            (__attribute__((address_space(3))) void*)(uint32_t)(uintptr_t)dp,
            16, 0, 0);
      }
    };

    STAGE(0, 0);
    for (int kc = 0; kc < KCN; ++kc) {
      asm volatile("s_waitcnt vmcnt(0)" ::: "memory"); // own chunk-kc loads done
      __builtin_amdgcn_s_barrier();                    // all waves staged + prev buf free
      if (kc < KCN - 1) STAGE(kc + 1, (kc + 1) & 1);
      const f16* Lb = &lds[kc & 1][0];
#pragma unroll
      for (int kk = 0; kk < 4; ++kk) {
        f16x8 a[4], b[2];
#pragma unroll
        for (int e = 0; e < 4; ++e)
          a[e] = *(const f16x8*)(Lb + ((((ew * 4 + e) * 4 + kk)) << 9) + lane * 8);
#pragma unroll
        for (int x2 = 0; x2 < 2; ++x2)
          b[x2] = *(const f16x8*)(Lb + ((32 + (bw * 2 + x2) * 4 + kk) << 9) + lane * 8);
#pragma unroll
        for (int e = 0; e < 4; ++e) {
          acc0[e] = __builtin_amdgcn_mfma_f32_32x32x16_f16(a[e], b[0], acc0[e], 0, 0, 0);
          acc1[e] = __builtin_amdgcn_mfma_f32_32x32x16_f16(a[e], b[1], acc1[e], 0, 0, 0);
        }
      }
    }

    // insert: C/D map (verified): col=lane&31, row=(q&3)+8*(q>>2)+4*(lane>>5)
#pragma unroll
    for (int e = 0; e < 4; ++e) {
      int ebase = e32base * 32 + (ew * 4 + e) * 32 + 4 * (lane >> 5);
#pragma unroll
      for (int q = 0; q < 16; ++q) {
        int eidx = ebase + (q & 3) + 8 * (q >> 2);
        float s0 = acc0[e][q];
        if (eidx < M_ROWS && s0 > ts0[9]) ins10(ts0, ti0, s0, eidx);
        float s1 = acc1[e][q];
        if (eidx < M_ROWS && s1 > ts1[9]) ins10(ts1, ti1, s1, eidx);
      }
    }
  }

  // ---- merge per batch-col: 4 lists (2 evid-waves x 2 lane-halves) -> top-12
  __syncthreads();
  float* ds = (float*)&lds[0][0];                 // 10240 floats (40KB)
  int*   di = (int*)((char*)&lds[0][0] + 40 * 1024);
  {
    int half = lane >> 5, cl = lane & 31;
    int base0 = ((((ew * 2 + half) * 4 + bw) * 2 + 0) * 32 + cl) * 10;
    int base1 = ((((ew * 2 + half) * 4 + bw) * 2 + 1) * 32 + cl) * 10;
#pragma unroll
    for (int q = 0; q < 10; ++q) {
      ds[base0 + q] = ts0[q]; di[base0 + q] = ti0[q];
      ds[base1 + q] = ts1[q]; di[base1 + q] = ti1[q];
    }
  }
  __syncthreads();
  if (t < 256) {
    int c = t; int bw2 = c >> 6, bt2 = (c >> 5) & 1, cl2 = c & 31;
    int hb[4];
#pragma unroll
    for (int u = 0; u < 4; ++u) {
      int ew2 = u >> 1, h2 = u & 1;
      hb[u] = ((((ew2 * 2 + h2) * 4 + bw2) * 2 + bt2) * 32 + cl2) * 10;
    }
    const int row = bb * 256 + c;
    float* ocs = cs + ((size_t)row * NGRP + g) * CAND;
    int*   oci = ci + ((size_t)row * NGRP + g) * CAND;
    for (int o = 0; o < CAND; ++o) {
      float best = -INFINITY; int bidx = 0x7fffffff; int bu = 0, bq = 0;
#pragma unroll
      for (int u = 0; u < 4; ++u) {
        for (int q = 0; q < 10; ++q) {
          float s = ds[hb[u] + q]; int id = di[hb[u] + q];
          if (s > best || (s == best && id < bidx)) { best = s; bidx = id; bu = u; bq = q; }
        }
      }
      ds[hb[bu] + bq] = -INFINITY;
      ocs[o] = best; oci[o] = bidx;
    }
  }
}

// ---------------------------------------------------------------------------
// Final: per row merge 16*12=192 candidates -> approx top-16 -> fp64 rescore
// -> exact-ordered top-10 (this stage gave absmax 0 in round 2).
// ---------------------------------------------------------------------------
__global__ __launch_bounds__(64) void final_merge(
    const float* __restrict__ x, const float* __restrict__ E,
    const float* __restrict__ cs, const int* __restrict__ ci,
    float* __restrict__ out)
{
  __shared__ float ls[192]; __shared__ int li[192];
  __shared__ int c16[16]; __shared__ double rs[16];
  const int row = blockIdx.x;
  const int lane = threadIdx.x;
  for (int q = lane; q < 192; q += 64) {
    ls[q] = cs[(size_t)row * 192 + q];
    li[q] = ci[(size_t)row * 192 + q];
  }
  __syncthreads();

  for (int o = 0; o < 16; ++o) {
    float bs = -INFINITY; int bi = 0x7fffffff; int bp = 0;
    for (int q = lane; q < 192; q += 64) {
      float s = ls[q];
      if (s > bs || (s == bs && li[q] < bi)) { bs = s; bi = li[q]; bp = q; }
    }
#pragma unroll
    for (int mk = 1; mk <= 32; mk <<= 1) {
      float qs = __shfl_xor(bs, mk, 64);
      int   qi = __shfl_xor(bi, mk, 64);
      int   qp = __shfl_xor(bp, mk, 64);
      if (qs > bs || (qs == bs && qi < bi)) { bs = qs; bi = qi; bp = qp; }
    }
    if (lane == 0) { c16[o] = bi; ls[bp] = -INFINITY; }
    __syncthreads();
  }

  {
    int cd = lane >> 2, p = lane & 3;
    int cid = c16[cd];
    const float* Er = E + (size_t)cid * D_DIM + p * 192;
    const float* Xr = x + (size_t)row * D_DIM + p * 192;
    double s = 0.0;
#pragma unroll 8
    for (int d = 0; d < 192; ++d) s += (double)Xr[d] * (double)Er[d];
    s += __shfl_xor(s, 1, 64);
    s += __shfl_xor(s, 2, 64);
    if (p == 0) rs[cd] = s;
  }
  __syncthreads();

  if (lane == 0) {
    for (int o = 0; o < K_TOP; ++o) {
      double bs = rs[0]; int bc = c16[0]; int b = 0;
      for (int q = 1; q < 16; ++q) {
        double v = rs[q]; int cq = c16[q];
        if (v > bs || (v == bs && cq < bc)) { bs = v; bc = cq; b = q; }
      }
      out[(size_t)row * K_TOP + o] = (float)bs;
      out[(size_t)B_ROWS * K_TOP + (size_t)row * K_TOP + o] = (float)bc;
      rs[b] = -1.0e300;
    }
  }
}

// ---------------------------------------------------------------------------
// Fallback (round-2 kernel, passed at 36 ms) if ws_size is insufficient.
// ---------------------------------------------------------------------------
#define RB   16
#define GQ   64
#define MMF  4
#define NJ   391
#define NTF  1024
#define XPAD 772
#define DQ4  192

__global__ __launch_bounds__(NTF, 4) void retr_fused(
    const float* __restrict__ x, const float* __restrict__ E,
    float* __restrict__ out)
{
  __shared__ float smem[21248];
  const int t = threadIdx.x;
  const int r = t & 15;
  const int g = t >> 4;
  const int rb0 = blockIdx.x * RB;
  {
    const float4* xg = (const float4*)(x + (size_t)rb0 * D_DIM);
    for (int q = t; q < RB * DQ4; q += NTF) {
      int row = q / DQ4, c4 = q % DQ4;
      float4 v = xg[q];
      *(float4*)(smem + row * XPAD + c4 * 4) = v;
    }
  }
  __syncthreads();
  float ts[K_TOP]; int ti[K_TOP];
#pragma unroll
  for (int q = 0; q < K_TOP; ++q) { ts[q] = -INFINITY; ti[q] = 0x7fffffff; }
  const float4* xr4 = (const float4*)(smem + r * XPAD);
  for (int j = 0; j < NJ; ++j) {
    const int m0 = (g + (j << 6)) * MMF;
    const float4* ep[MMF];
#pragma unroll
    for (int mm = 0; mm < MMF; ++mm) {
      int ml = m0 + mm;
      int mc = (ml < M_ROWS) ? ml : (M_ROWS - 1);
      ep[mm] = (const float4*)(E + (size_t)mc * D_DIM);
    }
    float4 acc[MMF];
#pragma unroll
    for (int mm = 0; mm < MMF; ++mm) acc[mm] = make_float4(0.f, 0.f, 0.f, 0.f);
#pragma unroll 4
    for (int dq = 0; dq < DQ4; ++dq) {
      float4 xv = xr4[dq];
#pragma unroll
      for (int mm = 0; mm < MMF; ++mm) {
        float4 e = ep[mm][dq];
        acc[mm].x += e.x * xv.x; acc[mm].y += e.y * xv.y;
        acc[mm].z += e.z * xv.z; acc[mm].w += e.w * xv.w;
      }
    }
#pragma unroll
    for (int mm = 0; mm < MMF; ++mm) {
      int ml = m0 + mm;
      float s = (acc[mm].x + acc[mm].y) + (acc[mm].z + acc[mm].w);
      if (ml < M_ROWS && s > ts[K_TOP - 1]) {
        ts[K_TOP - 1] = s; ti[K_TOP - 1] = ml;
#pragma unroll
        for (int q = K_TOP - 1; q > 0; --q) {
          if (ts[q] > ts[q - 1]) {
            float tf = ts[q]; ts[q] = ts[q - 1]; ts[q - 1] = tf;
            int   tq = ti[q]; ti[q] = ti[q - 1]; ti[q - 1] = tq;
          }
        }
      }
    }
  }
  __syncthreads();
  float*  cs  = smem;
  int*    ci  = (int*)(smem + 10240);
  int*    cnd = (int*)(smem + 20480);
  double* rsd = (double*)(smem + 20736);
#pragma unroll
  for (int q = 0; q < K_TOP; ++q) {
    cs[(r * GQ + g) * K_TOP + q] = ts[q];
    ci[(r * GQ + g) * K_TOP + q] = ti[q];
  }
  __syncthreads();
  const int w = t >> 6;
  const int lane = t & 63;
  {
    float ms[K_TOP]; int mi[K_TOP];
#pragma unroll
    for (int q = 0; q < K_TOP; ++q) {
      ms[q] = cs[(w * GQ + lane) * K_TOP + q];
      mi[q] = ci[(w * GQ + lane) * K_TOP + q];
    }
    for (int o = 0; o < 16; ++o) {
      float hs = ms[0]; int hi = mi[0];
      float bs = hs;    int bi = hi;
#pragma unroll
      for (int mk = 1; mk <= 32; mk <<= 1) {
        float qs = __shfl_xor(bs, mk, 64);
        int   qi = __shfl_xor(bi, mk, 64);
        if (qs > bs || (qs == bs && qi < bi)) { bs = qs; bi = qi; }
      }
      bool win = (hs == bs) && (hi == bi);
      if (win) {
#pragma unroll
        for (int q = 0; q < K_TOP - 1; ++q) { ms[q] = ms[q + 1]; mi[q] = mi[q + 1]; }
        ms[K_TOP - 1] = -INFINITY; mi[K_TOP - 1] = 0x7fffffff;
      }
      if (lane == 0) cnd[w * 16 + o] = bi;
    }
  }
  __syncthreads();
  {
    int cand = lane >> 2, p = lane & 3;
    int cid = cnd[w * 16 + cand];
    const float* Er = E + (size_t)cid * D_DIM + p * 192;
    const float* Xr = x + (size_t)(rb0 + w) * D_DIM + p * 192;
    double s = 0.0;
#pragma unroll 8
    for (int d = 0; d < 192; ++d) s += (double)Xr[d] * (double)Er[d];
    s += __shfl_xor(s, 1, 64);
    s += __shfl_xor(s, 2, 64);
    if (p == 0) rsd[w * 16 + cand] = s;
  }
  __syncthreads();
  if (lane == 0) {
    const int row = rb0 + w;
    for (int o = 0; o < K_TOP; ++o) {
      double bsv = rsd[w * 16 + 0]; int bci = cnd[w * 16 + 0]; int b = 0;
      for (int q = 1; q < 16; ++q) {
        double v = rsd[w * 16 + q]; int c = cnd[w * 16 + q];
        if (v > bsv || (v == bsv && c < bci)) { bsv = v; bci = c; b = q; }
      }
      out[(size_t)row * K_TOP + o] = (float)bsv;
      out[(size_t)B_ROWS * K_TOP + (size_t)row * K_TOP + o] = (float)bci;
      rsd[w * 16 + b] = -1.0e300;
    }
  }
}

// ---------------------------------------------------------------------------
extern "C" void kernel_launch(void* const* d_in, const int* in_sizes, int n_in,
                              void* d_out, int out_size, void* d_ws, size_t ws_size,
                              hipStream_t stream) {
  const float* x = (const float*)d_in[0];
  const float* E = (const float*)d_in[1];
  float* out = (float*)d_out;

  if (ws_size < WS_NEED) {
    // not enough scratch for the f16 copies: safe fp32 fallback (~36 ms)
    retr_fused<<<dim3(B_ROWS / RB), NTF, 0, stream>>>(x, E, out);
    return;
  }

  f16*   Xfp = (f16*)d_ws;
  f16*   Efp = (f16*)((char*)d_ws + EF_OFF);
  float* csp = (float*)((char*)d_ws + CS_OFF);
  int*   cip = (int*)((char*)d_ws + CI_OFF);

  convert_frag<<<dim3((B32N * KSTEPS * 64) / 256), 256, 0, stream>>>(x, Xfp, B32N);
  convert_frag<<<dim3((E32N * KSTEPS * 64) / 256), 256, 0, stream>>>(E, Efp, E32N);
  gemm_topk<<<dim3(NBB, NGRP), 512, 0, stream>>>(Efp, Xfp, csp, cip);
  final_merge<<<dim3(B_ROWS), 64, 0, stream>>>(x, E, csp, cip, out);
}

// Round 4
// 941.492 us; speedup vs baseline: 38.4603x; 1.8736x over previous
//
#include <hip/hip_runtime.h>
#include <math.h>
#include <stdint.h>

#define B_ROWS 4096
#define D_DIM  768
#define M_ROWS 100000
#define K_TOP  10

// ---------------- MFMA-path constants ----------------
#define KSTEPS 48          // 768 / 16
#define E32N   3125        // evidence 32-row tiles
#define B32N   128         // batch 32-row tiles
#define NGRP   16          // evidence groups
#define NBB    16          // batch blocks (256 rows each)
#define NITER_TOT 391      // ceil(3125/8)
#define CAND   12          // candidates kept per (row, group)
#define KCN    12          // k-chunks of 64
#define LTK    6           // per-lane top-k length

typedef _Float16 f16;
typedef _Float16 f16x8 __attribute__((ext_vector_type(8)));
typedef float   f32x16 __attribute__((ext_vector_type(16)));

// workspace layout (bytes)
#define XF_BYTES (128ull * 48 * 1024)
#define EF_OFF   XF_BYTES
#define EF_BYTES (3125ull * 48 * 1024)
#define CS_OFF   (EF_OFF + EF_BYTES)
#define CS_BYTES (4096ull * NGRP * CAND * 4)
#define CI_OFF   (CS_OFF + CS_BYTES)
#define CI_BYTES (4096ull * NGRP * CAND * 4)
#define WS_NEED  (CI_OFF + CI_BYTES)

// ---------------------------------------------------------------------------
// Convert fp32 [rows][768] -> f16 fragment-tiled [band32][ks48][lane64][j8].
// frag value (l,j) = src[band*32 + (l&31)][ks*16 + 8*(l>>5) + j]
// ---------------------------------------------------------------------------
__global__ __launch_bounds__(256) void convert_frag(
    const float* __restrict__ src, f16* __restrict__ dst, int nband)
{
  int tid  = blockIdx.x * 256 + threadIdx.x;
  int l    = tid & 63;
  int rest = tid >> 6;
  int ks   = rest % KSTEPS;
  int band = rest / KSTEPS;
  if (band >= nband) return;
  int row = band * 32 + (l & 31);
  int k0  = ks * 16 + 8 * (l >> 5);
  const float* s = src + (size_t)row * D_DIM + k0;
  float4 v0 = *(const float4*)s;
  float4 v1 = *(const float4*)(s + 4);
  f16x8 o;
  o[0] = (f16)v0.x; o[1] = (f16)v0.y; o[2] = (f16)v0.z; o[3] = (f16)v0.w;
  o[4] = (f16)v1.x; o[5] = (f16)v1.y; o[6] = (f16)v1.z; o[7] = (f16)v1.w;
  *(f16x8*)(dst + (((size_t)band * KSTEPS + ks) << 9) + l * 8) = o;
}

// sorted top-6 insert (descending), static-indexed
__device__ __forceinline__ void ins6(float (&ts)[LTK], int (&ti)[LTK],
                                     float s, int idx)
{
  ts[LTK - 1] = s; ti[LTK - 1] = idx;
#pragma unroll
  for (int q = LTK - 1; q > 0; --q) {
    if (ts[q] > ts[q - 1]) {
      float a = ts[q]; ts[q] = ts[q - 1]; ts[q - 1] = a;
      int   b = ti[q]; ti[q] = ti[q - 1]; ti[q - 1] = b;
    }
  }
}

__device__ __forceinline__ float max16(const f32x16& v)
{
  float a = fmaxf(fmaxf(v[0], v[1]), fmaxf(v[2], v[3]));
  float b = fmaxf(fmaxf(v[4], v[5]), fmaxf(v[6], v[7]));
  float c = fmaxf(fmaxf(v[8], v[9]), fmaxf(v[10], v[11]));
  float d = fmaxf(fmaxf(v[12], v[13]), fmaxf(v[14], v[15]));
  return fmaxf(fmaxf(a, b), fmaxf(c, d));
}

// ---------------------------------------------------------------------------
// GEMM + fused per-lane top-k.  8 waves = 2 evid-waves x 4 batch-waves.
// Per block-iteration: 256 evid rows x 256 batch cols, K=768.
// Per wave: 4 evid-tiles x 2 batch-tiles of mfma_f32_32x32x16_f16 (A=E so
// C col = lane&31 = batch col -> topk is lane-local).
// Staging roles are wave-uniform: waves 0..3 stage E (2 e32-tiles each),
// waves 4..7 stage X (2 b32-tiles each); each tile = contiguous 4 KB per kc.
// ---------------------------------------------------------------------------
__global__ __launch_bounds__(512, 2) void gemm_topk(
    const f16* __restrict__ Ef, const f16* __restrict__ Xf,
    float* __restrict__ cs, int* __restrict__ ci)
{
  __shared__ f16 lds[2][32768];   // 2 x 64KB; frags 0..31 = E, 32..63 = X

  const int t    = threadIdx.x;
  const int lane = t & 63;
  const int w    = t >> 6;      // 0..7
  const int ew   = w >> 2;      // 0..1  evid-wave
  const int bw   = w & 3;       // 0..3  batch-wave

  // XCD-aware remap of the 256 blocks: ids congruent mod 8 share an XCD;
  // give each XCD all 16 batch-blocks of 2 evidence groups.
  const int id = blockIdx.x;
  const int g  = (id & 7) + 8 * (id >> 7);        // evidence group 0..15
  const int bb = (id >> 3) & 15;                  // batch block 0..15
  const int niter = 24 + (g < (NITER_TOT - 16 * 24) ? 1 : 0);

  // staging sources (X-wave source is j-invariant)
  const bool isE = (w < 4);
  const f16* xsrc0 = Xf + (((size_t)(bb * 8 + 2 * (w - 4)) * KSTEPS) << 9);
  const f16* xsrc1 = Xf + (((size_t)(bb * 8 + 2 * (w - 4) + 1) * KSTEPS) << 9);
  const uint32_t dstE0 = (isE ? (2 * w) * 2048 : 16384 + 2 * (w - 4) * 2048);
  const uint32_t dstE1 = dstE0 + 2048;            // f16-element offsets

  float ts0[LTK], ts1[LTK]; int ti0[LTK], ti1[LTK];
#pragma unroll
  for (int q = 0; q < LTK; ++q) {
    ts0[q] = -INFINITY; ts1[q] = -INFINITY;
    ti0[q] = 0x7fffffff; ti1[q] = 0x7fffffff;
  }

  for (int j = 0; j < niter; ++j) {
    const int it = g + NGRP * j;
    const int e32base = it * 8;

    const f16 *s0, *s1;
    if (isE) {
      int ea = e32base + 2 * w;     if (ea > E32N - 1) ea = E32N - 1;
      int eb = e32base + 2 * w + 1; if (eb > E32N - 1) eb = E32N - 1;
      s0 = Ef + (((size_t)ea * KSTEPS) << 9);
      s1 = Ef + (((size_t)eb * KSTEPS) << 9);
    } else { s0 = xsrc0; s1 = xsrc1; }

    f32x16 acc0[4], acc1[4];
#pragma unroll
    for (int e = 0; e < 4; ++e) {
#pragma unroll
      for (int q = 0; q < 16; ++q) { acc0[e][q] = 0.f; acc1[e][q] = 0.f; }
    }

    auto STAGE = [&](int kc, int bufi) {
      const f16* a0 = s0 + ((size_t)kc << 11) + lane * 8;   // kc*2048 elems
      const f16* a1 = s1 + ((size_t)kc << 11) + lane * 8;
      f16* d0 = &lds[bufi][0] + dstE0 + lane * 8;
      f16* d1 = &lds[bufi][0] + dstE1 + lane * 8;
#pragma unroll
      for (int ff = 0; ff < 4; ++ff) {
        __builtin_amdgcn_global_load_lds(
            (const __attribute__((address_space(1))) void*)(uintptr_t)(a0 + ff * 512),
            (__attribute__((address_space(3))) void*)(uint32_t)(uintptr_t)(d0 + ff * 512),
            16, 0, 0);
      }
#pragma unroll
      for (int ff = 0; ff < 4; ++ff) {
        __builtin_amdgcn_global_load_lds(
            (const __attribute__((address_space(1))) void*)(uintptr_t)(a1 + ff * 512),
            (__attribute__((address_space(3))) void*)(uint32_t)(uintptr_t)(d1 + ff * 512),
            16, 0, 0);
      }
    };

    STAGE(0, 0);
    for (int kc = 0; kc < KCN; ++kc) {
      asm volatile("s_waitcnt vmcnt(0)" ::: "memory"); // own kc loads landed
      __builtin_amdgcn_s_barrier();                    // all waves staged
      if (kc < KCN - 1) STAGE(kc + 1, (kc + 1) & 1);
      const f16* Lb = &lds[kc & 1][0];
#pragma unroll
      for (int kk = 0; kk < 4; ++kk) {
        f16x8 a[4], b[2];
#pragma unroll
        for (int e = 0; e < 4; ++e)
          a[e] = *(const f16x8*)(Lb + ((((ew * 4 + e) * 4 + kk)) << 9) + lane * 8);
#pragma unroll
        for (int x2 = 0; x2 < 2; ++x2)
          b[x2] = *(const f16x8*)(Lb + ((32 + (bw * 2 + x2) * 4 + kk) << 9) + lane * 8);
#pragma unroll
        for (int e = 0; e < 4; ++e) {
          acc0[e] = __builtin_amdgcn_mfma_f32_32x32x16_f16(a[e], b[0], acc0[e], 0, 0, 0);
          acc1[e] = __builtin_amdgcn_mfma_f32_32x32x16_f16(a[e], b[1], acc1[e], 0, 0, 0);
        }
      }
    }

    // inserts, max-prefiltered per 16-value tile
    // C/D map: col=lane&31, row=(q&3)+8*(q>>2)+4*(lane>>5)
#pragma unroll
    for (int e = 0; e < 4; ++e) {
      const int ebase = e32base * 32 + (ew * 4 + e) * 32 + 4 * (lane >> 5);
      if (max16(acc0[e]) > ts0[LTK - 1]) {
#pragma unroll
        for (int q = 0; q < 16; ++q) {
          int eidx = ebase + (q & 3) + 8 * (q >> 2);
          float s = acc0[e][q];
          if (eidx < M_ROWS && s > ts0[LTK - 1]) ins6(ts0, ti0, s, eidx);
        }
      }
      if (max16(acc1[e]) > ts1[LTK - 1]) {
#pragma unroll
        for (int q = 0; q < 16; ++q) {
          int eidx = ebase + (q & 3) + 8 * (q >> 2);
          float s = acc1[e][q];
          if (eidx < M_ROWS && s > ts1[LTK - 1]) ins6(ts1, ti1, s, eidx);
        }
      }
    }
  }

  // ---- merge per batch-col: 4 lists (2 evid-waves x 2 lane-halves) -> top-12
  __syncthreads();
  float* ds = (float*)&lds[0][0];                      // 6144 floats (24 KB)
  int*   di = (int*)((char*)&lds[0][0] + 32 * 1024);
  {
    int half = lane >> 5, cl = lane & 31;
    int base0 = ((((ew * 2 + half) * 4 + bw) * 2 + 0) * 32 + cl) * LTK;
    int base1 = ((((ew * 2 + half) * 4 + bw) * 2 + 1) * 32 + cl) * LTK;
#pragma unroll
    for (int q = 0; q < LTK; ++q) {
      ds[base0 + q] = ts0[q]; di[base0 + q] = ti0[q];
      ds[base1 + q] = ts1[q]; di[base1 + q] = ti1[q];
    }
  }
  __syncthreads();
  if (t < 256) {
    int c = t; int bw2 = c >> 6, bt2 = (c >> 5) & 1, cl2 = c & 31;
    int hb[4];
#pragma unroll
    for (int u = 0; u < 4; ++u) {
      int ew2 = u >> 1, h2 = u & 1;
      hb[u] = ((((ew2 * 2 + h2) * 4 + bw2) * 2 + bt2) * 32 + cl2) * LTK;
    }
    const int row = bb * 256 + c;
    float* ocs = cs + ((size_t)row * NGRP + g) * CAND;
    int*   oci = ci + ((size_t)row * NGRP + g) * CAND;
    for (int o = 0; o < CAND; ++o) {
      float best = -INFINITY; int bidx = 0x7fffffff; int bu = 0, bq = 0;
#pragma unroll
      for (int u = 0; u < 4; ++u) {
        for (int q = 0; q < LTK; ++q) {
          float s = ds[hb[u] + q]; int id2 = di[hb[u] + q];
          if (s > best || (s == best && id2 < bidx)) { best = s; bidx = id2; bu = u; bq = q; }
        }
      }
      ds[hb[bu] + bq] = -INFINITY;
      ocs[o] = best; oci[o] = bidx;
    }
  }
}

// ---------------------------------------------------------------------------
// Final: per row merge 16*12=192 candidates -> approx top-16 -> fp64 rescore
// -> exact-ordered top-10 (absmax 0 in rounds 2 and 3).
// ---------------------------------------------------------------------------
__global__ __launch_bounds__(64) void final_merge(
    const float* __restrict__ x, const float* __restrict__ E,
    const float* __restrict__ cs, const int* __restrict__ ci,
    float* __restrict__ out)
{
  __shared__ float ls[192]; __shared__ int li[192];
  __shared__ int c16[16]; __shared__ double rs[16];
  const int row = blockIdx.x;
  const int lane = threadIdx.x;
  for (int q = lane; q < 192; q += 64) {
    ls[q] = cs[(size_t)row * 192 + q];
    li[q] = ci[(size_t)row * 192 + q];
  }
  __syncthreads();

  for (int o = 0; o < 16; ++o) {
    float bs = -INFINITY; int bi = 0x7fffffff; int bp = 0;
    for (int q = lane; q < 192; q += 64) {
      float s = ls[q];
      if (s > bs || (s == bs && li[q] < bi)) { bs = s; bi = li[q]; bp = q; }
    }
#pragma unroll
    for (int mk = 1; mk <= 32; mk <<= 1) {
      float qs = __shfl_xor(bs, mk, 64);
      int   qi = __shfl_xor(bi, mk, 64);
      int   qp = __shfl_xor(bp, mk, 64);
      if (qs > bs || (qs == bs && qi < bi)) { bs = qs; bi = qi; bp = qp; }
    }
    if (lane == 0) { c16[o] = bi; ls[bp] = -INFINITY; }
    __syncthreads();
  }

  {
    int cd = lane >> 2, p = lane & 3;
    int cid = c16[cd];
    const float* Er = E + (size_t)cid * D_DIM + p * 192;
    const float* Xr = x + (size_t)row * D_DIM + p * 192;
    double s = 0.0;
#pragma unroll 8
    for (int d = 0; d < 192; ++d) s += (double)Xr[d] * (double)Er[d];
    s += __shfl_xor(s, 1, 64);
    s += __shfl_xor(s, 2, 64);
    if (p == 0) rs[cd] = s;
  }
  __syncthreads();

  if (lane == 0) {
    for (int o = 0; o < K_TOP; ++o) {
      double bs = rs[0]; int bc = c16[0]; int b = 0;
      for (int q = 1; q < 16; ++q) {
        double v = rs[q]; int cq = c16[q];
        if (v > bs || (v == bs && cq < bc)) { bs = v; bc = cq; b = q; }
      }
      out[(size_t)row * K_TOP + o] = (float)bs;
      out[(size_t)B_ROWS * K_TOP + (size_t)row * K_TOP + o] = (float)bc;
      rs[b] = -1.0e300;
    }
  }
}

// ---------------------------------------------------------------------------
// Fallback (round-2 kernel) if ws_size is insufficient.
// ---------------------------------------------------------------------------
#define RB   16
#define GQ   64
#define MMF  4
#define NJ   391
#define NTF  1024
#define XPAD 772
#define DQ4  192

__global__ __launch_bounds__(NTF, 4) void retr_fused(
    const float* __restrict__ x, const float* __restrict__ E,
    float* __restrict__ out)
{
  __shared__ float smem[21248];
  const int t = threadIdx.x;
  const int r = t & 15;
  const int g = t >> 4;
  const int rb0 = blockIdx.x * RB;
  {
    const float4* xg = (const float4*)(x + (size_t)rb0 * D_DIM);
    for (int q = t; q < RB * DQ4; q += NTF) {
      int row = q / DQ4, c4 = q % DQ4;
      float4 v = xg[q];
      *(float4*)(smem + row * XPAD + c4 * 4) = v;
    }
  }
  __syncthreads();
  float ts[K_TOP]; int ti[K_TOP];
#pragma unroll
  for (int q = 0; q < K_TOP; ++q) { ts[q] = -INFINITY; ti[q] = 0x7fffffff; }
  const float4* xr4 = (const float4*)(smem + r * XPAD);
  for (int j = 0; j < NJ; ++j) {
    const int m0 = (g + (j << 6)) * MMF;
    const float4* ep[MMF];
#pragma unroll
    for (int mm = 0; mm < MMF; ++mm) {
      int ml = m0 + mm;
      int mc = (ml < M_ROWS) ? ml : (M_ROWS - 1);
      ep[mm] = (const float4*)(E + (size_t)mc * D_DIM);
    }
    float4 acc[MMF];
#pragma unroll
    for (int mm = 0; mm < MMF; ++mm) acc[mm] = make_float4(0.f, 0.f, 0.f, 0.f);
#pragma unroll 4
    for (int dq = 0; dq < DQ4; ++dq) {
      float4 xv = xr4[dq];
#pragma unroll
      for (int mm = 0; mm < MMF; ++mm) {
        float4 e = ep[mm][dq];
        acc[mm].x += e.x * xv.x; acc[mm].y += e.y * xv.y;
        acc[mm].z += e.z * xv.z; acc[mm].w += e.w * xv.w;
      }
    }
#pragma unroll
    for (int mm = 0; mm < MMF; ++mm) {
      int ml = m0 + mm;
      float s = (acc[mm].x + acc[mm].y) + (acc[mm].z + acc[mm].w);
      if (ml < M_ROWS && s > ts[K_TOP - 1]) {
        ts[K_TOP - 1] = s; ti[K_TOP - 1] = ml;
#pragma unroll
        for (int q = K_TOP - 1; q > 0; --q) {
          if (ts[q] > ts[q - 1]) {
            float tf = ts[q]; ts[q] = ts[q - 1]; ts[q - 1] = tf;
            int   tq = ti[q]; ti[q] = ti[q - 1]; ti[q - 1] = tq;
          }
        }
      }
    }
  }
  __syncthreads();
  float*  cs  = smem;
  int*    ci  = (int*)(smem + 10240);
  int*    cnd = (int*)(smem + 20480);
  double* rsd = (double*)(smem + 20736);
#pragma unroll
  for (int q = 0; q < K_TOP; ++q) {
    cs[(r * GQ + g) * K_TOP + q] = ts[q];
    ci[(r * GQ + g) * K_TOP + q] = ti[q];
  }
  __syncthreads();
  const int w = t >> 6;
  const int lane = t & 63;
  {
    float ms[K_TOP]; int mi[K_TOP];
#pragma unroll
    for (int q = 0; q < K_TOP; ++q) {
      ms[q] = cs[(w * GQ + lane) * K_TOP + q];
      mi[q] = ci[(w * GQ + lane) * K_TOP + q];
    }
    for (int o = 0; o < 16; ++o) {
      float hs = ms[0]; int hi = mi[0];
      float bs = hs;    int bi = hi;
#pragma unroll
      for (int mk = 1; mk <= 32; mk <<= 1) {
        float qs = __shfl_xor(bs, mk, 64);
        int   qi = __shfl_xor(bi, mk, 64);
        if (qs > bs || (qs == bs && qi < bi)) { bs = qs; bi = qi; }
      }
      bool win = (hs == bs) && (hi == bi);
      if (win) {
#pragma unroll
        for (int q = 0; q < K_TOP - 1; ++q) { ms[q] = ms[q + 1]; mi[q] = mi[q + 1]; }
        ms[K_TOP - 1] = -INFINITY; mi[K_TOP - 1] = 0x7fffffff;
      }
      if (lane == 0) cnd[w * 16 + o] = bi;
    }
  }
  __syncthreads();
  {
    int cand = lane >> 2, p = lane & 3;
    int cid = cnd[w * 16 + cand];
    const float* Er = E + (size_t)cid * D_DIM + p * 192;
    const float* Xr = x + (size_t)(rb0 + w) * D_DIM + p * 192;
    double s = 0.0;
#pragma unroll 8
    for (int d = 0; d < 192; ++d) s += (double)Xr[d] * (double)Er[d];
    s += __shfl_xor(s, 1, 64);
    s += __shfl_xor(s, 2, 64);
    if (p == 0) rsd[w * 16 + cand] = s;
  }
  __syncthreads();
  if (lane == 0) {
    const int row = rb0 + w;
    for (int o = 0; o < K_TOP; ++o) {
      double bsv = rsd[w * 16 + 0]; int bci = cnd[w * 16 + 0]; int b = 0;
      for (int q = 1; q < 16; ++q) {
        double v = rsd[w * 16 + q]; int c = cnd[w * 16 + q];
        if (v > bsv || (v == bsv && c < bci)) { bsv = v; bci = c; b = q; }
      }
      out[(size_t)row * K_TOP + o] = (float)bsv;
      out[(size_t)B_ROWS * K_TOP + (size_t)row * K_TOP + o] = (float)bci;
      rsd[w * 16 + b] = -1.0e300;
    }
  }
}

// ---------------------------------------------------------------------------
extern "C" void kernel_launch(void* const* d_in, const int* in_sizes, int n_in,
                              void* d_out, int out_size, void* d_ws, size_t ws_size,
                              hipStream_t stream) {
  const float* x = (const float*)d_in[0];
  const float* E = (const float*)d_in[1];
  float* out = (float*)d_out;

  if (ws_size < WS_NEED) {
    retr_fused<<<dim3(B_ROWS / RB), NTF, 0, stream>>>(x, E, out);
    return;
  }

  f16*   Xfp = (f16*)d_ws;
  f16*   Efp = (f16*)((char*)d_ws + EF_OFF);
  float* csp = (float*)((char*)d_ws + CS_OFF);
  int*   cip = (int*)((char*)d_ws + CI_OFF);

  convert_frag<<<dim3((B32N * KSTEPS * 64) / 256), 256, 0, stream>>>(x, Xfp, B32N);
  convert_frag<<<dim3((E32N * KSTEPS * 64) / 256), 256, 0, stream>>>(E, Efp, E32N);
  gemm_topk<<<dim3(NBB * NGRP), 512, 0, stream>>>(Efp, Xfp, csp, cip);
  final_merge<<<dim3(B_ROWS), 64, 0, stream>>>(x, E, csp, cip, out);
}